// Round 8
// baseline (256.244 us; speedup 1.0000x reference)
//
#include <hip/hip_runtime.h>

typedef short bf16x8 __attribute__((ext_vector_type(8)));
typedef float f32x4  __attribute__((ext_vector_type(4)));

#define NROW  16384
#define DD    512
#define VOCAB 8192
#define VS    4
#define VCH   2048           // vocab rows per split
#define BM    256            // vocab tile
#define BN    256            // x-row tile
#define BK    64
#define NCHUNK 8             // VCH/BM
#define NKT    8             // DD/BK
#define NTILE  64            // NCHUNK*NKT

// ---- out-buffer scratch layout (float words); all overwritten by final z_q ----
#define CBBF_W   4194304                 // cb normalized bf16 after x bf16
#define CANDV_W  6291456                 // fallback: [8][16384][2] float
#define CANDI_W  6815744                 // fallback: [8][16384][2] int
#define OUT_IDX  ((size_t)NROW * DD)
#define OUT_ENT  (OUT_IDX + NROW)
#define OUT_MEAN (OUT_ENT + 1)

// ---- ws layout (words) ----
#define WS_CBNORM 0
#define WS_MAXSIM 16384
#define WS_COUNTS 32768
#define WS_CANDV  49152
#define WS_CANDI  311296
#define WS_NEED_BYTES ((size_t)(311296 + 262144) * 4)   // 2,293,760 B

#define GLD_LDS(g, l) \
    __builtin_amdgcn_global_load_lds((const __attribute__((address_space(1))) void*)(g), \
                                     (__attribute__((address_space(3))) void*)(l), 16, 0, 0)

#define BAR()   __builtin_amdgcn_s_barrier()
#define LGKM0() asm volatile("s_waitcnt lgkmcnt(0)" ::: "memory")
#define VM4()   asm volatile("s_waitcnt vmcnt(4)" ::: "memory")
#define VM0()   asm volatile("s_waitcnt vmcnt(0)" ::: "memory")

__device__ __forceinline__ ushort f2bf(float f) {
    unsigned u = __float_as_uint(f);
    return (ushort)((u + 0x7fffu + ((u >> 16) & 1u)) >> 16);   // RNE
}

// ---------------- fused prep: x->bf16, cb->normalized bf16 + norms, zero counts ----------------
__global__ void eq_prep(const float* __restrict__ x, const float* __restrict__ cb,
                        ushort* __restrict__ xbf, ushort* __restrict__ cbbf,
                        float* __restrict__ nrm, int* __restrict__ counts) {
    const int b = blockIdx.x;
    const int tid = threadIdx.x;
    if (b < 4096) {
        size_t i = ((size_t)b * 256 + tid) * 8;
        float4 v0 = *(const float4*)(x + i);
        float4 v1 = *(const float4*)(x + i + 4);
        ushort r[8] = {f2bf(v0.x), f2bf(v0.y), f2bf(v0.z), f2bf(v0.w),
                       f2bf(v1.x), f2bf(v1.y), f2bf(v1.z), f2bf(v1.w)};
        *(uint4*)(xbf + i) = *(const uint4*)r;
        return;
    }
    const int bb = b - 4096;                    // 0..2047
    if (bb < 32) counts[bb * 256 + tid] = 0;    // zero histogram (8192 ints)
    const int row = bb * 4 + (tid >> 6);        // 4 waves, 1 cb row each
    const int l = tid & 63;
    const float* p = cb + (size_t)row * DD;
    float4 a = *(const float4*)(p + l * 4);
    float4 bq = *(const float4*)(p + 256 + l * 4);
    float s = a.x * a.x + a.y * a.y + a.z * a.z + a.w * a.w
            + bq.x * bq.x + bq.y * bq.y + bq.z * bq.z + bq.w * bq.w;
#pragma unroll
    for (int off = 32; off > 0; off >>= 1) s += __shfl_xor(s, off, 64);
    float n = fmaxf(sqrtf(s), 1e-12f);
    float rn = 1.0f / n;
    ushort r0[4] = {f2bf(a.x * rn), f2bf(a.y * rn), f2bf(a.z * rn), f2bf(a.w * rn)};
    ushort r1[4] = {f2bf(bq.x * rn), f2bf(bq.y * rn), f2bf(bq.z * rn), f2bf(bq.w * rn)};
    *(uint2*)(cbbf + (size_t)row * DD + l * 4)       = *(const uint2*)r0;
    *(uint2*)(cbbf + (size_t)row * DD + 256 + l * 4) = *(const uint2*)r1;
    if (l == 0) nrm[row] = n;
}

// ---------------- MFMA candidate pass: 8-phase, row-split half-tiles ----------------
// Half-tile = 128 rows x 128 B (full BK). Slot swizzle phys = slot ^ (row&7);
// linear gload_lds dest, inverse permutation in the global source (rule #21).
// Stage placement: B(t+1) in P1/P2; A(t+2) in P4; one counted gate vmcnt(4)/tile.
// Block->XCD mapping (xcd = bid%8 round-robin): all 4 vsplits of each xtile on
// the SAME XCD -> per-XCD L2 working set = 8 xtiles x 256KB B (2MB, chunk
// re-reads hit L2) + ~1MB streaming A chunks (8-way shared).
__global__ __launch_bounds__(512, 2) void eq_gemm_topk(
    const ushort* __restrict__ xbf, const ushort* __restrict__ cbbf,
    float* __restrict__ candval, int* __restrict__ candidx) {
    __shared__ __align__(16) char LDS[131072];   // A: 2set x 2half x 16KB; B same @65536
    const int tid = threadIdx.x;
    const int lane = tid & 63;
    const int w = tid >> 6;          // 0..7
    const int wm = w >> 2;           // 0..1  -> 128 vocab rows
    const int wn = w & 3;            // 0..3  -> 64 x rows
    const int c = lane & 15, q = lane >> 4;

    const int bid = blockIdx.x;                  // 0..255
    const int j = bid >> 3;                      // 0..31
    const int vsplit = j & 3;
    const int xtile  = (bid & 7) * 8 + (j >> 2); // XCD-local: 8 xtiles x 4 vsplits
    const int xbase  = xtile * BN;
    const int vsbase = vsplit * VCH;

    const char* gA = (const char*)cbbf + (size_t)vsbase * 1024;   // 1024 B per row
    const char* gB = (const char*)xbf  + (size_t)xbase  * 1024;
    // staging: unit u = w*64+lane (+512 for 2nd load) -> row u>>3, phys slot u&7,
    // logical slot = (u&7) ^ ((u>>3)&7); w*8 == 0 mod 8 so lane expression only
    const int thrOff = (w * 8 + (lane >> 3)) * 1024
                     + (((lane & 7) ^ ((lane >> 3) & 7)) << 4);
    const int wbase = w * 1024;
    // read side: row r (r&7 == c&7), logical slot s*4+q at phys (s*4+q)^(r&7)
    const int sw0 = (q ^ (c & 7)) << 4;
    const int sw1 = ((4 + q) ^ (c & 7)) << 4;
    const int aoff0 = wm * 16384 + c * 128 + sw0;
    const int aoff1 = wm * 16384 + c * 128 + sw1;
    const int bbase = 65536 + (wn >> 1) * 16384 + ((wn & 1) * 64 + c) * 128;
    const int boff0 = bbase + sw0;
    const int boff1 = bbase + sw1;

#define STAGE_A(lin2, h) do { int _l = (lin2); if (_l < NTILE) { \
        const char* _s = gA + ((_l >> 3) * 262144 + (h) * 131072 + (_l & 7) * 128) + thrOff; \
        char* _d = (char*)LDS + ((_l & 1) * 32768 + (h) * 16384 + wbase); \
        GLD_LDS(_s, _d); GLD_LDS(_s + 65536, _d + 8192); } } while (0)
#define STAGE_B(lin2, h) do { int _l = (lin2); if (_l < NTILE) { \
        const char* _s = gB + ((h) * 131072 + (_l & 7) * 128) + thrOff; \
        char* _d = (char*)LDS + (65536 + (_l & 1) * 32768 + (h) * 16384 + wbase); \
        GLD_LDS(_s, _d); GLD_LDS(_s + 65536, _d + 8192); } } while (0)

    int t1k[4], t2k[4];
#pragma unroll
    for (int nj = 0; nj < 4; ++nj) { t1k[nj] = 0x80000000; t2k[nj] = 0x80000000; }

    f32x4 acc[8][4];

    // prologue: A(0),B(0),A(1); drain A(0)+B(0), leave A(1) in flight
    STAGE_A(0, 0); STAGE_A(0, 1);
    STAGE_B(0, 0); STAGE_B(0, 1);
    STAGE_A(1, 0); STAGE_A(1, 1);
    VM4(); BAR();

    for (int lin = 0; lin < NTILE; ++lin) {
        const int set = (lin & 1) * 32768;
        if ((lin & 7) == 0) {
#pragma unroll
            for (int mi = 0; mi < 8; ++mi)
#pragma unroll
                for (int nj = 0; nj < 4; ++nj) acc[mi][nj] = (f32x4){0.f, 0.f, 0.f, 0.f};
        }
        bf16x8 af[8], bf0, bf1;
        // ---- phase 1: s=0, nj 0/1; stage B-half0(t+1) ----
#pragma unroll
        for (int mi = 0; mi < 8; ++mi)
            af[mi] = *(const bf16x8*)(LDS + set + aoff0 + mi * 2048);
        bf0 = *(const bf16x8*)(LDS + set + boff0);
        bf1 = *(const bf16x8*)(LDS + set + boff0 + 2048);
        STAGE_B(lin + 1, 0);
        BAR(); LGKM0();
        __builtin_amdgcn_s_setprio(1);
#pragma unroll
        for (int mi = 0; mi < 8; ++mi) {
            acc[mi][0] = __builtin_amdgcn_mfma_f32_16x16x32_bf16(af[mi], bf0, acc[mi][0], 0, 0, 0);
            acc[mi][1] = __builtin_amdgcn_mfma_f32_16x16x32_bf16(af[mi], bf1, acc[mi][1], 0, 0, 0);
        }
        __builtin_amdgcn_s_setprio(0);
        BAR();
        // ---- phase 2: s=0, nj 2/3; stage B-half1(t+1) ----
        bf0 = *(const bf16x8*)(LDS + set + boff0 + 4096);
        bf1 = *(const bf16x8*)(LDS + set + boff0 + 6144);
        STAGE_B(lin + 1, 1);
        BAR(); LGKM0();
        __builtin_amdgcn_s_setprio(1);
#pragma unroll
        for (int mi = 0; mi < 8; ++mi) {
            acc[mi][2] = __builtin_amdgcn_mfma_f32_16x16x32_bf16(af[mi], bf0, acc[mi][2], 0, 0, 0);
            acc[mi][3] = __builtin_amdgcn_mfma_f32_16x16x32_bf16(af[mi], bf1, acc[mi][3], 0, 0, 0);
        }
        __builtin_amdgcn_s_setprio(0);
        BAR();
        // ---- phase 3: s=1, nj 0/1 (no stage) ----
#pragma unroll
        for (int mi = 0; mi < 8; ++mi)
            af[mi] = *(const bf16x8*)(LDS + set + aoff1 + mi * 2048);
        bf0 = *(const bf16x8*)(LDS + set + boff1);
        bf1 = *(const bf16x8*)(LDS + set + boff1 + 2048);
        BAR(); LGKM0();
        __builtin_amdgcn_s_setprio(1);
#pragma unroll
        for (int mi = 0; mi < 8; ++mi) {
            acc[mi][0] = __builtin_amdgcn_mfma_f32_16x16x32_bf16(af[mi], bf0, acc[mi][0], 0, 0, 0);
            acc[mi][1] = __builtin_amdgcn_mfma_f32_16x16x32_bf16(af[mi], bf1, acc[mi][1], 0, 0, 0);
        }
        __builtin_amdgcn_s_setprio(0);
        BAR();
        // ---- phase 4: s=1, nj 2/3; stage A(t+2) both halves; counted gate ----
        bf0 = *(const bf16x8*)(LDS + set + boff1 + 4096);
        bf1 = *(const bf16x8*)(LDS + set + boff1 + 6144);
        STAGE_A(lin + 2, 0);
        STAGE_A(lin + 2, 1);
        if (lin < 62) { VM4(); } else { VM0(); }
        BAR(); LGKM0();
        __builtin_amdgcn_s_setprio(1);
#pragma unroll
        for (int mi = 0; mi < 8; ++mi) {
            acc[mi][2] = __builtin_amdgcn_mfma_f32_16x16x32_bf16(af[mi], bf0, acc[mi][2], 0, 0, 0);
            acc[mi][3] = __builtin_amdgcn_mfma_f32_16x16x32_bf16(af[mi], bf1, acc[mi][3], 0, 0, 0);
        }
        __builtin_amdgcn_s_setprio(0);
        BAR();
        // ---- chunk fold: packed-key top-2 (5 VALU/value) ----
        if ((lin & 7) == 7) {
            const int chb = (lin >> 3) << 5;
#pragma unroll
            for (int nj = 0; nj < 4; ++nj)
#pragma unroll
                for (int mi = 0; mi < 8; ++mi)
#pragma unroll
                    for (int r = 0; r < 4; ++r) {
                        int key = (__float_as_int(acc[mi][nj][r]) & (int)0xFFFFFF00)
                                | (chb + mi * 4 + r);
                        int mn = t1k[nj] < key ? t1k[nj] : key;
                        t1k[nj] = t1k[nj] < key ? key : t1k[nj];
                        t2k[nj] = t2k[nj] < mn ? mn : t2k[nj];
                    }
        }
    }
    // decode keys -> (value, vocab idx), exact merge across the 4 q-lanes
#pragma unroll
    for (int nj = 0; nj < 4; ++nj) {
        int k1 = t1k[nj], k2 = t2k[nj];
        float t1v = __int_as_float(k1 & (int)0xFFFFFF00);
        float t2v = __int_as_float(k2 & (int)0xFFFFFF00);
        int l1 = k1 & 255, l2 = k2 & 255;
        int t1i = vsbase + ((l1 >> 5) << 8) + (wm << 7) + (((l1 >> 2) & 7) << 4) + (q << 2) + (l1 & 3);
        int t2i = vsbase + ((l2 >> 5) << 8) + (wm << 7) + (((l2 >> 2) & 7) << 4) + (q << 2) + (l2 & 3);
#pragma unroll
        for (int off = 16; off <= 32; off <<= 1) {
            float o1v = __shfl_xor(t1v, off, 64); int o1i = __shfl_xor(t1i, off, 64);
            float o2v = __shfl_xor(t2v, off, 64); int o2i = __shfl_xor(t2i, off, 64);
            bool wbest = (t1v > o1v) || (t1v == o1v && t1i < o1i);
            float m1 = wbest ? t1v : o1v;  int m1i = wbest ? t1i : o1i;
            float ca = wbest ? o1v : t1v;  int cai = wbest ? o1i : t1i;
            float cw = wbest ? t2v : o2v;  int cwi = wbest ? t2i : o2i;
            bool s2 = (ca > cw) || (ca == cw && cai < cwi);
            t1v = m1;           t1i = m1i;
            t2v = s2 ? ca : cw; t2i = s2 ? cai : cwi;
        }
        if (q == 0) {
            int list = vsplit * 2 + wm;
            int row = xbase + wn * 64 + nj * 16 + c;
            size_t base = ((size_t)list * NROW + row) * 2;
            candval[base] = t1v; candval[base + 1] = t2v;
            candidx[base] = t1i; candidx[base + 1] = t2i;
        }
    }
#undef STAGE_A
#undef STAGE_B
}

// ---------------- fp64 rescore with margin prefilter (+ optional fused z_q gather) ----------------
template <bool FUSE_ZQ>
__device__ __forceinline__ void rescore_body(
    const float* __restrict__ x, const float* __restrict__ cb,
    const float* __restrict__ cbnorm,
    const float* __restrict__ candval, const int* __restrict__ candidx,
    float* __restrict__ out, float* __restrict__ maxsim, int* __restrict__ counts) {
    int w = threadIdx.x >> 6, l = threadIdx.x & 63;
    int row = blockIdx.x * 4 + w;

    const float4* X4 = (const float4*)(x + (size_t)row * DD);
    float4 xa = X4[l], xb = X4[l + 64];
    float s2 = xa.x * xa.x + xa.y * xa.y + xa.z * xa.z + xa.w * xa.w
             + xb.x * xb.x + xb.y * xb.y + xb.z * xb.z + xb.w * xb.w;
#pragma unroll
    for (int off = 32; off > 0; off >>= 1) s2 += __shfl_xor(s2, off, 64);
    float xn = fmaxf(sqrtf(s2), 1e-12f);
    double xd[8] = {(double)(xa.x / xn), (double)(xa.y / xn), (double)(xa.z / xn),
                    (double)(xa.w / xn), (double)(xb.x / xn), (double)(xb.y / xn),
                    (double)(xb.z / xn), (double)(xb.w / xn)};

    float cv[16]; int ci[16];
#pragma unroll
    for (int t = 0; t < 16; ++t) {
        size_t b = ((size_t)(t >> 1) * NROW + row) * 2 + (t & 1);
        cv[t] = candval[b]; ci[t] = candidx[b];
    }
    float bv1 = cv[0];
#pragma unroll
    for (int t = 1; t < 16; ++t) bv1 = fmaxf(bv1, cv[t]);
    // candval scale is ||x||*sim; bf16 noise ~1e-4*||x|| + 3e-5 key trunc -> 2e-3 covers
    float margin = 2e-3f * xn;

    double best = -1e300; int bi = 1 << 30;
    for (int t = 0; t < 16; ++t) {
        if (cv[t] >= bv1 - margin) {                 // wave-uniform branch
            float n = cbnorm[ci[t]];
            const float4* C4 = (const float4*)(cb + (size_t)ci[t] * DD);
            float4 ca = C4[l], cb4 = C4[l + 64];
            double a = xd[0] * (double)(ca.x / n) + xd[1] * (double)(ca.y / n)
                     + xd[2] * (double)(ca.z / n) + xd[3] * (double)(ca.w / n)
                     + xd[4] * (double)(cb4.x / n) + xd[5] * (double)(cb4.y / n)
                     + xd[6] * (double)(cb4.z / n) + xd[7] * (double)(cb4.w / n);
#pragma unroll
            for (int off = 32; off > 0; off >>= 1) a += __shfl_xor(a, off, 64);
            bool better = (a > best) || (a == best && ci[t] < bi);
            best = better ? a : best;     // wave-uniform after reduction
            bi = better ? ci[t] : bi;
        }
    }
    if (l == 0) {
        out[OUT_IDX + row] = (float)bi;
        maxsim[row] = (float)best;
        atomicAdd(counts + bi, 1);
    }
    if (FUSE_ZQ) {
        const float4* src = (const float4*)(cb + (size_t)bi * DD);
        float4* dst = (float4*)(out + (size_t)row * DD);
        dst[l] = src[l];
        dst[l + 64] = src[l + 64];
    }
}

__global__ void eq_rescore(const float* __restrict__ x, const float* __restrict__ cb,
                           const float* __restrict__ cbnorm,
                           const float* __restrict__ candval, const int* __restrict__ candidx,
                           float* __restrict__ out, float* __restrict__ maxsim,
                           int* __restrict__ counts) {
    rescore_body<false>(x, cb, cbnorm, candval, candidx, out, maxsim, counts);
}

__global__ void eq_rescore_fused(const float* __restrict__ x, const float* __restrict__ cb,
                                 const float* __restrict__ cbnorm,
                                 const float* __restrict__ candval, const int* __restrict__ candidx,
                                 float* __restrict__ out, float* __restrict__ maxsim,
                                 int* __restrict__ counts) {
    rescore_body<true>(x, cb, cbnorm, candval, candidx, out, maxsim, counts);
}

// ---------------- z_q gather (fallback path only) ----------------
__global__ void eq_gather(const float* __restrict__ cb, float* __restrict__ out) {
    int w = threadIdx.x >> 6, l = threadIdx.x & 63;
    int row = blockIdx.x * 4 + w;
    int bi = (int)out[OUT_IDX + row];
    const float4* src = (const float4*)(cb + (size_t)bi * DD);
    float4* dst = (float4*)(out + (size_t)row * DD);
    dst[l] = src[l];
    dst[l + 64] = src[l + 64];
}

// ---------------- entropy + mean ----------------
__global__ void eq_entropy_mean(const int* __restrict__ counts,
                                const float* __restrict__ maxsim,
                                float* __restrict__ out) {
    __shared__ float red[16];
    int tid = threadIdx.x;   // 1024
    float s = 0.f;
    for (int b = tid; b < VOCAB; b += 1024) {
        int c = counts[b];
        if (c > 0) {
            float p = (float)c * (1.0f / 16384.0f);
            s += p * logf(p);
        }
    }
#pragma unroll
    for (int off = 32; off > 0; off >>= 1) s += __shfl_down(s, off, 64);
    if ((tid & 63) == 0) red[tid >> 6] = s;
    __syncthreads();
    if (tid == 0) {
        float t = 0.f;
#pragma unroll
        for (int i = 0; i < 16; ++i) t += red[i];
        out[OUT_ENT] = -t;
    }
    __syncthreads();
    float m = 0.f;
    for (int i = tid; i < NROW; i += 1024) m += maxsim[i];
#pragma unroll
    for (int off = 32; off > 0; off >>= 1) m += __shfl_down(m, off, 64);
    if ((tid & 63) == 0) red[tid >> 6] = m;
    __syncthreads();
    if (tid == 0) {
        float t = 0.f;
#pragma unroll
        for (int i = 0; i < 16; ++i) t += red[i];
        out[OUT_MEAN] = t * (1.0f / 16384.0f);
    }
}

extern "C" void kernel_launch(void* const* d_in, const int* in_sizes, int n_in,
                              void* d_out, int out_size, void* d_ws, size_t ws_size,
                              hipStream_t stream) {
    const float* x  = (const float*)d_in[0];
    const float* cb = (const float*)d_in[1];
    float* out = (float*)d_out;
    float* wsf = (float*)d_ws;
    int*   wsi = (int*)d_ws;

    float* cbnorm = wsf + WS_CBNORM;
    float* maxsim = wsf + WS_MAXSIM;
    int*   counts = wsi + WS_COUNTS;

    ushort* xbf   = (ushort*)out;                 // scratch in out
    ushort* cbbf  = (ushort*)(out + CBBF_W);

    const bool fused = ws_size >= WS_NEED_BYTES;  // deterministic per deployment
    float* candv = fused ? (wsf + WS_CANDV) : (out + CANDV_W);
    int*   candi = fused ? (wsi + WS_CANDI) : (int*)(out + CANDI_W);

    eq_prep<<<6144, 256, 0, stream>>>(x, cb, xbf, cbbf, cbnorm, counts);

    eq_gemm_topk<<<256, 512, 0, stream>>>(xbf, cbbf, candv, candi);

    if (fused) {
        eq_rescore_fused<<<NROW / 4, 256, 0, stream>>>(x, cb, cbnorm, candv, candi,
                                                       out, maxsim, counts);
    } else {
        eq_rescore<<<NROW / 4, 256, 0, stream>>>(x, cb, cbnorm, candv, candi,
                                                 out, maxsim, counts);
        eq_gather<<<NROW / 4, 256, 0, stream>>>(cb, out);
    }
    eq_entropy_mean<<<1, 1024, 0, stream>>>(counts, maxsim, out);
}